// Round 12
// baseline (779.991 us; speedup 1.0000x reference)
//
#include <hip/hip_runtime.h>
#include <hip/hip_bf16.h>

#define STEP_F (1.0f/9.0f)
#define REP 8

typedef float f4 __attribute__((ext_vector_type(4)));

// ---------------- conv1+conv2 fused ----------------
__global__ __launch_bounds__(256) void conv12_k(
    const float* __restrict__ x,
    const float* __restrict__ w1c, const float* __restrict__ b1c,
    const float* __restrict__ w2c, const float* __restrict__ b2c,
    const float* __restrict__ g, const float* __restrict__ be,
    const float* __restrict__ mn, const float* __restrict__ vr,
    float* __restrict__ y2)
{
    __shared__ float y1t[8 * 1188 + 16];
    #pragma unroll 1
    for (int rep = 0; rep < REP; ++rep) {
    const int b    = blockIdx.x;
    const int ohg  = blockIdx.y;
    const int tid  = threadIdx.x;
    const int rows = (127 - 8 * ohg) < 9 ? (127 - 8 * ohg) : 9;

    {
        const int owg = tid & 31;
        const int rg  = tid >> 5;
        const float* xb = x + (size_t)b * 3 * 65536;
        for (int r = rg; r < rows; r += 8) {
            const int r1  = 8 * ohg + r;
            const int ih0 = 2 * r1;
            const int iw0 = owg * 8;
            float acc1[8][4];
            #pragma unroll
            for (int c = 0; c < 8; ++c)
                #pragma unroll
                for (int t = 0; t < 4; ++t) acc1[c][t] = 0.0f;

            #pragma unroll
            for (int ci = 0; ci < 3; ++ci) {
                float rr[3][10];
                #pragma unroll
                for (int kh = 0; kh < 3; ++kh) {
                    const float* row = xb + ci * 65536 + (ih0 + kh) * 256;
                    #pragma unroll
                    for (int t = 0; t < 5; ++t) {
                        int c = iw0 + 2 * t; if (c > 254) c = 254;
                        float2 v = *(const float2*)(row + c);
                        rr[kh][2*t] = v.x; rr[kh][2*t+1] = v.y;
                    }
                }
                #pragma unroll
                for (int co = 0; co < 8; ++co) {
                    float wr[9];
                    #pragma unroll
                    for (int k = 0; k < 9; ++k) wr[k] = w1c[(co * 3 + ci) * 9 + k];
                    #pragma unroll
                    for (int t = 0; t < 4; ++t) {
                        float a = acc1[co][t];
                        #pragma unroll
                        for (int kh = 0; kh < 3; ++kh)
                            a = fmaf(rr[kh][2*t+0], wr[kh*3+0],
                                fmaf(rr[kh][2*t+1], wr[kh*3+1],
                                fmaf(rr[kh][2*t+2], wr[kh*3+2], a)));
                        acc1[co][t] = a;
                    }
                }
            }
            #pragma unroll
            for (int co = 0; co < 8; ++co) {
                float bs = b1c[co];
                f4 o;
                o[0] = fmaxf(acc1[co][0] + bs, 0.0f);
                o[1] = fmaxf(acc1[co][1] + bs, 0.0f);
                o[2] = fmaxf(acc1[co][2] + bs, 0.0f);
                o[3] = fmaxf(acc1[co][3] + bs, 0.0f);
                *(f4*)&y1t[co * 1188 + r * 132 + owg * 4] = o;
            }
        }
    }
    __syncthreads();

    {
        const int lane = tid & 63;
        const int wv   = __builtin_amdgcn_readfirstlane(tid >> 6);
        const int ow   = lane;
        const int co0  = wv * 4;

        float acc[4][4];
        #pragma unroll
        for (int c = 0; c < 4; ++c)
            #pragma unroll
            for (int j = 0; j < 4; ++j) acc[c][j] = 0.0f;

        #pragma unroll 2
        for (int ci = 0; ci < 8; ++ci) {
            float wr[4][9];
            #pragma unroll
            for (int c = 0; c < 4; ++c) {
                const int wb = __builtin_amdgcn_readfirstlane(((co0 + c) * 8 + ci) * 9);
                #pragma unroll
                for (int k = 0; k < 9; ++k) wr[c][k] = w2c[wb + k];
            }
            const float* lci = y1t + ci * 1188;
            #pragma unroll
            for (int r = 0; r < 9; ++r) {
                float2 x01 = *(const float2*)&lci[r * 132 + 2 * ow];
                float  x2  = lci[r * 132 + 2 * ow + 2];
                #pragma unroll
                for (int kh = 0; kh < 3; ++kh) {
                    const int jj = r - kh;
                    if (jj >= 0 && (jj & 1) == 0 && (jj >> 1) < 4) {
                        const int j = jj >> 1;
                        #pragma unroll
                        for (int c = 0; c < 4; ++c)
                            acc[c][j] = fmaf(x01.x, wr[c][kh*3+0],
                                        fmaf(x01.y, wr[c][kh*3+1],
                                        fmaf(x2,    wr[c][kh*3+2], acc[c][j])));
                    }
                }
            }
        }

        if (ow < 63) {
            #pragma unroll
            for (int c = 0; c < 4; ++c) {
                const int co = co0 + c;
                const float bs = b2c[co];
                const float s  = g[co] / sqrtf(vr[co] + 1e-5f);
                const float sh = be[co] - mn[co] * s;
                #pragma unroll
                for (int j = 0; j < 4; ++j) {
                    int oh = 4 * blockIdx.y + j;
                    if (oh < 63)
                        y2[(((size_t)b * 16 + co) * 63 + oh) * 64 + ow] =
                            fmaxf(acc[c][j] + bs, 0.0f) * s + sh;
                }
            }
        }
    }
    __syncthreads();
    asm volatile("" ::: "memory");
    }
}

// ---------------- conv3 (R6-proven) ----------------
__global__ __launch_bounds__(256) void conv3_k(
    const float* __restrict__ x, const float* __restrict__ w,
    const float* __restrict__ bias,
    const float* __restrict__ g, const float* __restrict__ be,
    const float* __restrict__ mn, const float* __restrict__ vr,
    float* __restrict__ y)
{
    #pragma unroll 1
    for (int rep = 0; rep < REP; ++rep) {
    const int b   = blockIdx.x;
    const int ohg = blockIdx.y;
    const int coh = blockIdx.z;
    const int lane = threadIdx.x & 63;
    const int wv   = __builtin_amdgcn_readfirstlane(threadIdx.x >> 6);
    const int ow   = lane & 31;
    const int ohl  = lane >> 5;
    const int co0  = coh * 16 + wv * 4;
    const int ihb  = ohg * 8 + ohl * 4;

    float acc[4][2];
    #pragma unroll
    for (int c = 0; c < 4; ++c) { acc[c][0] = 0.0f; acc[c][1] = 0.0f; }

    #pragma unroll 4
    for (int ci = 0; ci < 16; ++ci) {
        const float* gp = x + (((size_t)b * 16 + ci) * 63) * 64 + 2 * ow;
        f4 rv[5];
        #pragma unroll
        for (int r = 0; r < 5; ++r) {
            int ih = ihb + r; ih = ih > 62 ? 62 : ih;
            rv[r] = *(const f4*)(gp + ih * 64);
        }
        float wr[4][9];
        #pragma unroll
        for (int c = 0; c < 4; ++c) {
            const int wb = __builtin_amdgcn_readfirstlane(((co0 + c) * 16 + ci) * 9);
            #pragma unroll
            for (int k = 0; k < 9; ++k) wr[c][k] = w[wb + k];
        }
        #pragma unroll
        for (int j = 0; j < 2; ++j)
            #pragma unroll
            for (int kh = 0; kh < 3; ++kh) {
                const f4 v = rv[2*j + kh];
                #pragma unroll
                for (int c = 0; c < 4; ++c)
                    acc[c][j] = fmaf(v[0], wr[c][kh*3+0],
                                fmaf(v[1], wr[c][kh*3+1],
                                fmaf(v[2], wr[c][kh*3+2], acc[c][j])));
            }
    }

    if (ow < 31) {
        #pragma unroll
        for (int c = 0; c < 4; ++c) {
            const int co = co0 + c;
            const float bs = bias[co];
            const float s  = g[co] / sqrtf(vr[co] + 1e-5f);
            const float sh = be[co] - mn[co] * s;
            #pragma unroll
            for (int j = 0; j < 2; ++j) {
                int oh = ohg * 4 + ohl * 2 + j;
                if (oh < 31)
                    y[(((size_t)b * 32 + co) * 31 + oh) * 32 + ow] =
                        fmaxf(acc[c][j] + bs, 0.0f) * s + sh;
            }
        }
    }
    asm volatile("" ::: "memory");
    }
}

// ---------------- conv4 (R6-proven) ----------------
__global__ __launch_bounds__(256) void conv4_k(
    const float* __restrict__ x, const float* __restrict__ w,
    const float* __restrict__ bias,
    const float* __restrict__ g, const float* __restrict__ be,
    const float* __restrict__ mn, const float* __restrict__ vr,
    float* __restrict__ y)
{
    #pragma unroll 1
    for (int rep = 0; rep < REP; ++rep) {
    const int b   = blockIdx.x;
    const int ohg = blockIdx.y;
    const int cog = blockIdx.z;
    const int lane = threadIdx.x & 63;
    const int wv   = __builtin_amdgcn_readfirstlane(threadIdx.x >> 6);
    const int ow   = lane & 15;
    const int ohl  = lane >> 4;
    const int oh   = ohg * 4 + ohl;
    const int co0  = cog * 16 + wv * 4;
    const int ihb  = 2 * oh;

    float acc[4];
    #pragma unroll
    for (int c = 0; c < 4; ++c) acc[c] = 0.0f;

    #pragma unroll 4
    for (int ci = 0; ci < 32; ++ci) {
        const float* gp = x + (((size_t)b * 32 + ci) * 31) * 32 + 2 * ow;
        f4 rv[3];
        #pragma unroll
        for (int r = 0; r < 3; ++r) {
            int ih = ihb + r; ih = ih > 30 ? 30 : ih;
            rv[r] = *(const f4*)(gp + ih * 32);
        }
        float wr[4][9];
        #pragma unroll
        for (int c = 0; c < 4; ++c) {
            const int wb = __builtin_amdgcn_readfirstlane(((co0 + c) * 32 + ci) * 9);
            #pragma unroll
            for (int k = 0; k < 9; ++k) wr[c][k] = w[wb + k];
        }
        #pragma unroll
        for (int kh = 0; kh < 3; ++kh) {
            const f4 v = rv[kh];
            #pragma unroll
            for (int c = 0; c < 4; ++c)
                acc[c] = fmaf(v[0], wr[c][kh*3+0],
                         fmaf(v[1], wr[c][kh*3+1],
                         fmaf(v[2], wr[c][kh*3+2], acc[c])));
        }
    }

    if (ow < 15 && oh < 15) {
        #pragma unroll
        for (int c = 0; c < 4; ++c) {
            const int co = co0 + c;
            const float bs = bias[co];
            const float s  = g[co] / sqrtf(vr[co] + 1e-5f);
            const float sh = be[co] - mn[co] * s;
            y[(((size_t)b * 64 + co) * 15 + oh) * 16 + ow] =
                fmaxf(acc[c] + bs, 0.0f) * s + sh;
        }
    }
    asm volatile("" ::: "memory");
    }
}

// ---------------- conv5 + mean, weights in LDS ----------------
__global__ __launch_bounds__(256) void conv5w_k(
    const float* __restrict__ x, const float* __restrict__ w,
    const float* __restrict__ bias,
    const float* __restrict__ g, const float* __restrict__ be,
    const float* __restrict__ mn, const float* __restrict__ vr,
    float* __restrict__ feat)
{
    __shared__ float lw[4608];
    __shared__ float red[4 * 580 + 16];
    #pragma unroll 1
    for (int rep = 0; rep < REP; ++rep) {
    const int b    = blockIdx.x;
    const int co0  = blockIdx.y * 8;
    const int tid  = threadIdx.x;

    {
        const float* wp = w + (size_t)co0 * 576;
        for (int i = tid; i < 4608; i += 256) lw[i] = wp[i];
    }
    __syncthreads();

    const int wv   = __builtin_amdgcn_readfirstlane(tid >> 6);
    const int lane = tid & 63;
    const int pr = lane >> 3, pc = lane & 7;

    float acc[8];
    #pragma unroll
    for (int c = 0; c < 8; ++c) acc[c] = 0.0f;

    #pragma unroll 2
    for (int i = 0; i < 16; ++i) {
        const int ci = wv * 16 + i;
        const float* gp = x + (((size_t)b * 64 + ci) * 15) * 16 + 2 * pc;
        f4 rv[3];
        #pragma unroll
        for (int r = 0; r < 3; ++r) {
            int ih = 2 * pr + r; ih = ih > 14 ? 14 : ih;
            rv[r] = *(const f4*)(gp + ih * 16);
        }
        float wr[8][9];
        #pragma unroll
        for (int c = 0; c < 8; ++c) {
            const float* lwp = lw + (c * 64 + ci) * 9;
            #pragma unroll
            for (int k = 0; k < 9; ++k) wr[c][k] = lwp[k];
        }
        #pragma unroll
        for (int kh = 0; kh < 3; ++kh) {
            const f4 v = rv[kh];
            #pragma unroll
            for (int c = 0; c < 8; ++c)
                acc[c] = fmaf(v[0], wr[c][kh*3+0],
                         fmaf(v[1], wr[c][kh*3+1],
                         fmaf(v[2], wr[c][kh*3+2], acc[c])));
        }
    }

    #pragma unroll
    for (int c = 0; c < 8; ++c) red[wv * 580 + lane * 9 + c] = acc[c];
    __syncthreads();
    if (wv == 0) {
        const bool act = (pr < 7) && (pc < 7);
        #pragma unroll
        for (int c = 0; c < 8; ++c) {
            float v = red[lane*9+c] + red[580+lane*9+c]
                    + red[1160+lane*9+c] + red[1740+lane*9+c];
            const int co = co0 + c;
            const float s = g[co] / sqrtf(vr[co] + 1e-5f);
            v = fmaxf(v + bias[co], 0.0f) * s + (be[co] - mn[co] * s);
            v = act ? v : 0.0f;
            #pragma unroll
            for (int off = 32; off; off >>= 1) v += __shfl_xor(v, off, 64);
            if (lane == 0) feat[(size_t)b * 128 + co] = v * (1.0f / 49.0f);
        }
    }
    __syncthreads();
    asm volatile("" ::: "memory");
    }
}

// ---------------- tail ----------------
__global__ __launch_bounds__(256) void tail_k(
    const float* __restrict__ featg, const float* __restrict__ l1w,
    const float* __restrict__ l1b, const float* __restrict__ l2w,
    const float* __restrict__ l2b, float* __restrict__ coef,
    float* __restrict__ spl)
{
    __shared__ float feat[128];
    __shared__ float hh[128];
    __shared__ float ysv[64];
    __shared__ float cfl[216];
    #pragma unroll 1
    for (int rep = 0; rep < REP; ++rep) {
    const int b = blockIdx.x, t = threadIdx.x;

    if (t < 128) feat[t] = featg[(size_t)b * 128 + t];
    __syncthreads();
    if (t < 128) {
        const float4* wp = (const float4*)(l1w + (size_t)t * 128);
        float s = l1b[t];
        #pragma unroll 8
        for (int k = 0; k < 32; ++k) {
            float4 v = wp[k];
            s += v.x*feat[4*k] + v.y*feat[4*k+1] + v.z*feat[4*k+2] + v.w*feat[4*k+3];
        }
        hh[t] = fmaxf(s, 0.0f);
    }
    __syncthreads();
    if (t < 60) {
        const float4* wp = (const float4*)(l2w + (size_t)t * 128);
        float s = l2b[t];
        #pragma unroll 8
        for (int k = 0; k < 32; ++k) {
            float4 v = wp[k];
            s += v.x*hh[4*k] + v.y*hh[4*k+1] + v.z*hh[4*k+2] + v.w*hh[4*k+3];
        }
        ysv[t] = s;
    }
    __syncthreads();
    if (t < 6) {
        const float h = STEP_F;
        float yt[10];
        #pragma unroll
        for (int n = 0; n < 10; ++n) yt[n] = ysv[t * 10 + n] + (float)n * h;
        float r[8];
        const float k6h2 = 6.0f / (h * h);
        #pragma unroll
        for (int i = 0; i < 8; ++i) r[i] = k6h2 * (yt[i] - 2.0f * yt[i+1] + yt[i+2]);
        float cp[8], dp[8];
        cp[0] = 0.25f; dp[0] = r[0] * 0.25f;
        #pragma unroll
        for (int i = 1; i < 8; ++i) {
            float m = 4.0f - cp[i-1];
            cp[i] = 1.0f / m;
            dp[i] = (r[i] - dp[i-1]) / m;
        }
        float M[10];
        M[0] = 0.0f; M[9] = 0.0f; M[8] = dp[7];
        #pragma unroll
        for (int i = 6; i >= 0; --i) M[i+1] = dp[i] - cp[i] * M[i+2];
        float* cg = coef + ((size_t)b * 6 + t) * 36;
        #pragma unroll
        for (int i = 0; i < 9; ++i) {
            float ca = (M[i+1] - M[i]) / (6.0f * h);
            float cb = M[i] * 0.5f;
            float cc = (yt[i+1] - yt[i]) / h - (M[i+1] + 2.0f * M[i]) * (h / 6.0f);
            float cd = yt[i];
            cfl[t*36 + i]      = ca;  cg[i]      = ca;
            cfl[t*36 + 9 + i]  = cb;  cg[9 + i]  = cb;
            cfl[t*36 + 18 + i] = cc;  cg[18 + i] = cc;
            cfl[t*36 + 27 + i] = cd;  cg[27 + i] = cd;
        }
    }
    __syncthreads();
    for (int i = t; i < 1530; i += 256) {
        int v = i % 255, ec = i / 255;
        float val = (float)v * (1.0f / 255.0f);
        int vi = (int)floorf(val / STEP_F);
        vi = vi < 0 ? 0 : (vi > 8 ? 8 : vi);
        float vf = val - (float)vi * STEP_F;
        const float* c = cfl + ec * 36;
        int e = ec / 3, ch = ec % 3;
        spl[(((size_t)e * 64 + b) * 3 + ch) * 255 + v] =
            ((c[vi]*vf + c[9+vi])*vf + c[18+vi])*vf + c[27+vi];
    }
    __syncthreads();
    asm volatile("" ::: "memory");
    }
}

// ---------------- apply ----------------
__global__ __launch_bounds__(256) void apply2_k(const float* __restrict__ batch,
                                                const float* __restrict__ coef,
                                                float* __restrict__ out)
{
    #pragma unroll 1
    for (int rep = 0; rep < REP; ++rep) {
    int bc = blockIdx.y;
    int b = bc / 3, ch = bc % 3;
    int lane = threadIdx.x & 63;
    int j = lane < 9 ? lane : 8;
    const float* c0p = coef + ((size_t)(b * 6 + 0 + ch)) * 36;
    const float* c1p = coef + ((size_t)(b * 6 + 3 + ch)) * 36;
    float A0 = c0p[j], B0 = c0p[9 + j], C0 = c0p[18 + j], D0 = c0p[27 + j];
    float A1 = c1p[j], B1 = c1p[9 + j], C1 = c1p[18 + j], D1 = c1p[27 + j];

    const int P = 65536;
    size_t base = ((size_t)b * 3 + ch) * P;
    int p0 = (blockIdx.x * blockDim.x + threadIdx.x) * 4;

    float4 xv = *(const float4*)(batch + base + p0);
    float xs[4] = {xv.x, xv.y, xv.z, xv.w};
    float r0[4], r1[4];
    #pragma unroll
    for (int k = 0; k < 4; ++k) {
        float x = xs[k];
        int xi = (int)floorf(x / STEP_F);
        xi = xi < 0 ? 0 : (xi > 8 ? 8 : xi);
        float xf = x - (float)xi * STEP_F;
        int bidx = xi << 2;
        float ga0 = __int_as_float(__builtin_amdgcn_ds_bpermute(bidx, __float_as_int(A0)));
        float gb0 = __int_as_float(__builtin_amdgcn_ds_bpermute(bidx, __float_as_int(B0)));
        float gc0 = __int_as_float(__builtin_amdgcn_ds_bpermute(bidx, __float_as_int(C0)));
        float gd0 = __int_as_float(__builtin_amdgcn_ds_bpermute(bidx, __float_as_int(D0)));
        float ga1 = __int_as_float(__builtin_amdgcn_ds_bpermute(bidx, __float_as_int(A1)));
        float gb1 = __int_as_float(__builtin_amdgcn_ds_bpermute(bidx, __float_as_int(B1)));
        float gc1 = __int_as_float(__builtin_amdgcn_ds_bpermute(bidx, __float_as_int(C1)));
        float gd1 = __int_as_float(__builtin_amdgcn_ds_bpermute(bidx, __float_as_int(D1)));
        r0[k] = fmaf(fmaf(fmaf(ga0, xf, gb0), xf, gc0), xf, gd0);
        r1[k] = fmaf(fmaf(fmaf(ga1, xf, gb1), xf, gc1), xf, gd1);
    }
    float4 o0 = {r0[0], r0[1], r0[2], r0[3]};
    float4 o1 = {r1[0], r1[1], r1[2], r1[3]};
    size_t off0 = (((size_t)0 * 64 + b) * 3 + ch) * P + p0;
    size_t off1 = (((size_t)1 * 64 + b) * 3 + ch) * P + p0;
    *(float4*)(out + off0) = o0;
    *(float4*)(out + off1) = o1;
    asm volatile("" ::: "memory");
    }
}

extern "C" void kernel_launch(void* const* d_in, const int* in_sizes, int n_in,
                              void* d_out, int out_size, void* d_ws, size_t ws_size,
                              hipStream_t stream) {
    const float* batch = (const float*)d_in[0];
    const float* w1 = (const float*)d_in[1];  const float* b1 = (const float*)d_in[2];
    const float* w2 = (const float*)d_in[3];  const float* b2 = (const float*)d_in[4];
    const float* w3 = (const float*)d_in[5];  const float* b3 = (const float*)d_in[6];
    const float* w4 = (const float*)d_in[7];  const float* b4 = (const float*)d_in[8];
    const float* w5 = (const float*)d_in[9];  const float* b5 = (const float*)d_in[10];
    const float* bn2g = (const float*)d_in[11]; const float* bn2b = (const float*)d_in[12];
    const float* bn2m = (const float*)d_in[13]; const float* bn2v = (const float*)d_in[14];
    const float* bn3g = (const float*)d_in[15]; const float* bn3b = (const float*)d_in[16];
    const float* bn3m = (const float*)d_in[17]; const float* bn3v = (const float*)d_in[18];
    const float* bn4g = (const float*)d_in[19]; const float* bn4b = (const float*)d_in[20];
    const float* bn4m = (const float*)d_in[21]; const float* bn4v = (const float*)d_in[22];
    const float* bn5g = (const float*)d_in[23]; const float* bn5b = (const float*)d_in[24];
    const float* bn5m = (const float*)d_in[25]; const float* bn5v = (const float*)d_in[26];
    const float* l1w = (const float*)d_in[27]; const float* l1b = (const float*)d_in[28];
    const float* l2w = (const float*)d_in[29]; const float* l2b = (const float*)d_in[30];

    float* outp = (float*)d_out;
    float* y2 = outp;                 // 64*16*63*64 = 4,128,768
    float* y3 = y2 + 4128768;         // 64*32*31*32 = 2,031,616
    float* y4 = y3 + 2031616;         // 64*64*15*16 =   983,040

    float* coef  = (float*)d_ws;      // 13,824 floats
    float* featw = coef + 13824;      // 8,192 floats
    float* spl   = outp + 25165824;

    const int TPB = 256;
    conv12_k<<<dim3(64, 16), TPB, 0, stream>>>(batch, w1, b1, w2, b2,
                                               bn2g, bn2b, bn2m, bn2v, y2);
    conv3_k<<<dim3(64, 8, 2), TPB, 0, stream>>>(y2, w3, b3, bn3g, bn3b, bn3m, bn3v, y3);
    conv4_k<<<dim3(64, 4, 4), TPB, 0, stream>>>(y3, w4, b4, bn4g, bn4b, bn4m, bn4v, y4);
    conv5w_k<<<dim3(64, 16), TPB, 0, stream>>>(y4, w5, b5, bn5g, bn5b, bn5m, bn5v, featw);
    tail_k<<<64, TPB, 0, stream>>>(featw, l1w, l1b, l2w, l2b, coef, spl);
    {
        dim3 grid(64, 192);
        apply2_k<<<grid, TPB, 0, stream>>>(batch, coef, outp);
    }
}

// Round 13
// 133.599 us; speedup vs baseline: 5.8383x; 5.8383x over previous
//
#include <hip/hip_runtime.h>
#include <hip/hip_bf16.h>

#define STEP_F (1.0f/9.0f)

typedef float f4 __attribute__((ext_vector_type(4)));

// ---------------- conv1: 3->8, 256x256 -> 127x127 (stored 127x128), stride 2, relu ----
__global__ __launch_bounds__(256) void conv1_k(const float* __restrict__ x,
                                               const float* __restrict__ w,
                                               const float* __restrict__ bias,
                                               float* __restrict__ y)
{
    int idx = blockIdx.x * 256 + threadIdx.x;
    int owg = idx & 31;
    int t1  = idx >> 5;
    int oh  = t1 % 127;
    int b   = t1 / 127;
    int iw0 = owg * 8;
    int ih0 = oh * 2;
    const float* xb = x + (size_t)b * 3 * 65536;

    float acc[8][4];
    #pragma unroll
    for (int c = 0; c < 8; ++c)
        #pragma unroll
        for (int t = 0; t < 4; ++t) acc[c][t] = 0.0f;

    #pragma unroll
    for (int ci = 0; ci < 3; ++ci) {
        float r[3][10];
        #pragma unroll
        for (int kh = 0; kh < 3; ++kh) {
            const float* row = xb + ci * 65536 + (ih0 + kh) * 256;
            #pragma unroll
            for (int t = 0; t < 5; ++t) {
                int c = iw0 + 2 * t; if (c > 254) c = 254;
                float2 v = *(const float2*)(row + c);
                r[kh][2*t] = v.x; r[kh][2*t+1] = v.y;
            }
        }
        #pragma unroll
        for (int co = 0; co < 8; ++co) {
            float wr[9];
            #pragma unroll
            for (int k = 0; k < 9; ++k) wr[k] = w[(co * 3 + ci) * 9 + k];
            #pragma unroll
            for (int t = 0; t < 4; ++t) {
                float a = acc[co][t];
                #pragma unroll
                for (int kh = 0; kh < 3; ++kh)
                    a = fmaf(r[kh][2*t+0], wr[kh*3+0],
                        fmaf(r[kh][2*t+1], wr[kh*3+1],
                        fmaf(r[kh][2*t+2], wr[kh*3+2], a)));
                acc[co][t] = a;
            }
        }
    }
    int ow0 = owg * 4;
    #pragma unroll
    for (int co = 0; co < 8; ++co) {
        float bs = bias[co];
        float4 o;
        o.x = fmaxf(acc[co][0] + bs, 0.0f);
        o.y = fmaxf(acc[co][1] + bs, 0.0f);
        o.z = fmaxf(acc[co][2] + bs, 0.0f);
        o.w = fmaxf(acc[co][3] + bs, 0.0f);
        *(float4*)(y + (((size_t)b * 8 + co) * 127 + oh) * 128 + ow0) = o;
    }
}

// ---------------- conv2: 8->16, LDS tile, full-width lanes (R6-proven) ----------
// Grid (16 ohg, 64 b): consecutive blocks share b -> same-XCD L2 locality on y1.
__global__ __launch_bounds__(256) void conv2_k(
    const float* __restrict__ x,      // y1 [64][8][127][128]
    const float* __restrict__ w, const float* __restrict__ bias,
    const float* __restrict__ g, const float* __restrict__ be,
    const float* __restrict__ mn, const float* __restrict__ vr,
    float* __restrict__ y)            // y2 [64][16][63][64]
{
    __shared__ float lds[8 * 9 * 128 + 192];
    const int ohg = blockIdx.x;       // 0..15
    const int b   = blockIdx.y;
    const int oh0 = ohg * 4;
    const int ih0 = oh0 * 2;
    const int tid = threadIdx.x;

    {
        const int col = tid & 127;
        const int rp  = tid >> 7;
        const int rows = (127 - ih0) < 9 ? (127 - ih0) : 9;
        #pragma unroll
        for (int ci = 0; ci < 8; ++ci) {
            const float* gp = x + (((size_t)b * 8 + ci) * 127 + ih0) * 128 + col;
            float* lp = lds + ci * 1152 + col;
            for (int rr = rp; rr < rows; rr += 2)
                lp[rr * 128] = gp[rr * 128];
        }
    }
    __syncthreads();

    const int lane = tid & 63;
    const int wv   = __builtin_amdgcn_readfirstlane(tid >> 6);
    const int ow   = lane;
    const int co0  = wv * 4;

    float acc[4][4];
    #pragma unroll
    for (int c = 0; c < 4; ++c)
        #pragma unroll
        for (int j = 0; j < 4; ++j) acc[c][j] = 0.0f;

    #pragma unroll 2
    for (int ci = 0; ci < 8; ++ci) {
        float wr[4][9];
        #pragma unroll
        for (int c = 0; c < 4; ++c) {
            const int wb = __builtin_amdgcn_readfirstlane(((co0 + c) * 8 + ci) * 9);
            #pragma unroll
            for (int k = 0; k < 9; ++k) wr[c][k] = w[wb + k];
        }
        const float* lci = lds + ci * 1152;
        #pragma unroll
        for (int r = 0; r < 9; ++r) {
            float2 x01 = *(const float2*)&lci[r * 128 + 2 * ow];
            float  x2  = lci[r * 128 + 2 * ow + 2];
            #pragma unroll
            for (int kh = 0; kh < 3; ++kh) {
                const int jj = r - kh;
                if (jj >= 0 && (jj & 1) == 0 && (jj >> 1) < 4) {
                    const int j = jj >> 1;
                    #pragma unroll
                    for (int c = 0; c < 4; ++c)
                        acc[c][j] = fmaf(x01.x, wr[c][kh*3+0],
                                    fmaf(x01.y, wr[c][kh*3+1],
                                    fmaf(x2,    wr[c][kh*3+2], acc[c][j])));
                }
            }
        }
    }

    if (ow < 63) {
        #pragma unroll
        for (int c = 0; c < 4; ++c) {
            const int co = co0 + c;
            const float bs = bias[co];
            const float s  = g[co] / sqrtf(vr[co] + 1e-5f);
            const float sh = be[co] - mn[co] * s;
            #pragma unroll
            for (int j = 0; j < 4; ++j) {
                int oh = oh0 + j;
                if (oh < 63)
                    y[(((size_t)b * 16 + co) * 63 + oh) * 64 + ow] =
                        fmaxf(acc[c][j] + bs, 0.0f) * s + sh;
            }
        }
    }
}

// ---------------- conv3: 16->32, direct-from-L2 (R6-proven, b-major locality) -------
// Grid (16 = ohg(8) x coh(2), 64 b).
__global__ __launch_bounds__(256) void conv3_k(
    const float* __restrict__ x,      // y2 [64][16][63][64]
    const float* __restrict__ w, const float* __restrict__ bias,
    const float* __restrict__ g, const float* __restrict__ be,
    const float* __restrict__ mn, const float* __restrict__ vr,
    float* __restrict__ y)            // y3 [64][32][31][32]
{
    const int ohg = blockIdx.x & 7;
    const int coh = blockIdx.x >> 3;
    const int b   = blockIdx.y;
    const int lane = threadIdx.x & 63;
    const int wv   = __builtin_amdgcn_readfirstlane(threadIdx.x >> 6);
    const int ow   = lane & 31;
    const int ohl  = lane >> 5;
    const int co0  = coh * 16 + wv * 4;
    const int ihb  = ohg * 8 + ohl * 4;

    float acc[4][2];
    #pragma unroll
    for (int c = 0; c < 4; ++c) { acc[c][0] = 0.0f; acc[c][1] = 0.0f; }

    #pragma unroll 4
    for (int ci = 0; ci < 16; ++ci) {
        const float* gp = x + (((size_t)b * 16 + ci) * 63) * 64 + 2 * ow;
        f4 rv[5];
        #pragma unroll
        for (int r = 0; r < 5; ++r) {
            int ih = ihb + r; ih = ih > 62 ? 62 : ih;
            rv[r] = *(const f4*)(gp + ih * 64);
        }
        float wr[4][9];
        #pragma unroll
        for (int c = 0; c < 4; ++c) {
            const int wb = __builtin_amdgcn_readfirstlane(((co0 + c) * 16 + ci) * 9);
            #pragma unroll
            for (int k = 0; k < 9; ++k) wr[c][k] = w[wb + k];
        }
        #pragma unroll
        for (int j = 0; j < 2; ++j)
            #pragma unroll
            for (int kh = 0; kh < 3; ++kh) {
                const f4 v = rv[2*j + kh];
                #pragma unroll
                for (int c = 0; c < 4; ++c)
                    acc[c][j] = fmaf(v[0], wr[c][kh*3+0],
                                fmaf(v[1], wr[c][kh*3+1],
                                fmaf(v[2], wr[c][kh*3+2], acc[c][j])));
            }
    }

    if (ow < 31) {
        #pragma unroll
        for (int c = 0; c < 4; ++c) {
            const int co = co0 + c;
            const float bs = bias[co];
            const float s  = g[co] / sqrtf(vr[co] + 1e-5f);
            const float sh = be[co] - mn[co] * s;
            #pragma unroll
            for (int j = 0; j < 2; ++j) {
                int oh = ohg * 4 + ohl * 2 + j;
                if (oh < 31)
                    y[(((size_t)b * 32 + co) * 31 + oh) * 32 + ow] =
                        fmaxf(acc[c][j] + bs, 0.0f) * s + sh;
            }
        }
    }
}

// ---------------- conv4: 32->64, direct-from-L2 (R6-proven, b-major locality) -------
// Grid (16 = ohg(4) x cog(4), 64 b).
__global__ __launch_bounds__(256) void conv4_k(
    const float* __restrict__ x,      // y3 [64][32][31][32]
    const float* __restrict__ w, const float* __restrict__ bias,
    const float* __restrict__ g, const float* __restrict__ be,
    const float* __restrict__ mn, const float* __restrict__ vr,
    float* __restrict__ y)            // y4 [64][64][15][16]
{
    const int ohg = blockIdx.x & 3;
    const int cog = blockIdx.x >> 2;
    const int b   = blockIdx.y;
    const int lane = threadIdx.x & 63;
    const int wv   = __builtin_amdgcn_readfirstlane(threadIdx.x >> 6);
    const int ow   = lane & 15;
    const int ohl  = lane >> 4;
    const int oh   = ohg * 4 + ohl;
    const int co0  = cog * 16 + wv * 4;
    const int ihb  = 2 * oh;

    float acc[4];
    #pragma unroll
    for (int c = 0; c < 4; ++c) acc[c] = 0.0f;

    #pragma unroll 4
    for (int ci = 0; ci < 32; ++ci) {
        const float* gp = x + (((size_t)b * 32 + ci) * 31) * 32 + 2 * ow;
        f4 rv[3];
        #pragma unroll
        for (int r = 0; r < 3; ++r) {
            int ih = ihb + r; ih = ih > 30 ? 30 : ih;
            rv[r] = *(const f4*)(gp + ih * 32);
        }
        float wr[4][9];
        #pragma unroll
        for (int c = 0; c < 4; ++c) {
            const int wb = __builtin_amdgcn_readfirstlane(((co0 + c) * 32 + ci) * 9);
            #pragma unroll
            for (int k = 0; k < 9; ++k) wr[c][k] = w[wb + k];
        }
        #pragma unroll
        for (int kh = 0; kh < 3; ++kh) {
            const f4 v = rv[kh];
            #pragma unroll
            for (int c = 0; c < 4; ++c)
                acc[c] = fmaf(v[0], wr[c][kh*3+0],
                         fmaf(v[1], wr[c][kh*3+1],
                         fmaf(v[2], wr[c][kh*3+2], acc[c])));
        }
    }

    if (ow < 15 && oh < 15) {
        #pragma unroll
        for (int c = 0; c < 4; ++c) {
            const int co = co0 + c;
            const float bs = bias[co];
            const float s  = g[co] / sqrtf(vr[co] + 1e-5f);
            const float sh = be[co] - mn[co] * s;
            y[(((size_t)b * 64 + co) * 15 + oh) * 16 + ow] =
                fmaxf(acc[c] + bs, 0.0f) * s + sh;
        }
    }
}

// ---------------- conv5 + BN + relu + mean: weights staged in LDS ----------------
// Grid (16 cog, 64 b). Zero s_loads in the inner loop.
__global__ __launch_bounds__(256) void conv5w_k(
    const float* __restrict__ x,      // y4 [64][64][15][16]
    const float* __restrict__ w, const float* __restrict__ bias,
    const float* __restrict__ g, const float* __restrict__ be,
    const float* __restrict__ mn, const float* __restrict__ vr,
    float* __restrict__ feat)         // [64][128]
{
    __shared__ float lw[4608];
    __shared__ float red[4 * 580 + 16];
    const int co0  = blockIdx.x * 8;
    const int b    = blockIdx.y;
    const int tid  = threadIdx.x;

    {
        const float* wp = w + (size_t)co0 * 576;
        for (int i = tid; i < 4608; i += 256) lw[i] = wp[i];
    }
    __syncthreads();

    const int wv   = __builtin_amdgcn_readfirstlane(tid >> 6);
    const int lane = tid & 63;
    const int pr = lane >> 3, pc = lane & 7;

    float acc[8];
    #pragma unroll
    for (int c = 0; c < 8; ++c) acc[c] = 0.0f;

    #pragma unroll 2
    for (int i = 0; i < 16; ++i) {
        const int ci = wv * 16 + i;
        const float* gp = x + (((size_t)b * 64 + ci) * 15) * 16 + 2 * pc;
        f4 rv[3];
        #pragma unroll
        for (int r = 0; r < 3; ++r) {
            int ih = 2 * pr + r; ih = ih > 14 ? 14 : ih;
            rv[r] = *(const f4*)(gp + ih * 16);
        }
        float wr[8][9];
        #pragma unroll
        for (int c = 0; c < 8; ++c) {
            const float* lwp = lw + (c * 64 + ci) * 9;   // wave-uniform -> broadcast
            #pragma unroll
            for (int k = 0; k < 9; ++k) wr[c][k] = lwp[k];
        }
        #pragma unroll
        for (int kh = 0; kh < 3; ++kh) {
            const f4 v = rv[kh];
            #pragma unroll
            for (int c = 0; c < 8; ++c)
                acc[c] = fmaf(v[0], wr[c][kh*3+0],
                         fmaf(v[1], wr[c][kh*3+1],
                         fmaf(v[2], wr[c][kh*3+2], acc[c])));
        }
    }

    #pragma unroll
    for (int c = 0; c < 8; ++c) red[wv * 580 + lane * 9 + c] = acc[c];
    __syncthreads();
    if (wv == 0) {
        const bool act = (pr < 7) && (pc < 7);
        #pragma unroll
        for (int c = 0; c < 8; ++c) {
            float v = red[lane*9+c] + red[580+lane*9+c]
                    + red[1160+lane*9+c] + red[1740+lane*9+c];
            const int co = co0 + c;
            const float s = g[co] / sqrtf(vr[co] + 1e-5f);
            v = fmaxf(v + bias[co], 0.0f) * s + (be[co] - mn[co] * s);
            v = act ? v : 0.0f;
            #pragma unroll
            for (int off = 32; off; off >>= 1) v += __shfl_xor(v, off, 64);
            if (lane == 0) feat[(size_t)b * 128 + co] = v * (1.0f / 49.0f);
        }
    }
}

// ---------------- fused tail: fc1 + fc2 + Thomas + splines LUT ----------------
__global__ __launch_bounds__(256) void tail_k(
    const float* __restrict__ featg, const float* __restrict__ l1w,
    const float* __restrict__ l1b, const float* __restrict__ l2w,
    const float* __restrict__ l2b, float* __restrict__ coef,
    float* __restrict__ spl)
{
    __shared__ float feat[128];
    __shared__ float hh[128];
    __shared__ float ysv[64];
    __shared__ float cfl[216];
    const int b = blockIdx.x, t = threadIdx.x;

    if (t < 128) feat[t] = featg[(size_t)b * 128 + t];
    __syncthreads();
    if (t < 128) {
        const float4* wp = (const float4*)(l1w + (size_t)t * 128);
        float s = l1b[t];
        #pragma unroll 8
        for (int k = 0; k < 32; ++k) {
            float4 v = wp[k];
            s += v.x*feat[4*k] + v.y*feat[4*k+1] + v.z*feat[4*k+2] + v.w*feat[4*k+3];
        }
        hh[t] = fmaxf(s, 0.0f);
    }
    __syncthreads();
    if (t < 60) {
        const float4* wp = (const float4*)(l2w + (size_t)t * 128);
        float s = l2b[t];
        #pragma unroll 8
        for (int k = 0; k < 32; ++k) {
            float4 v = wp[k];
            s += v.x*hh[4*k] + v.y*hh[4*k+1] + v.z*hh[4*k+2] + v.w*hh[4*k+3];
        }
        ysv[t] = s;
    }
    __syncthreads();
    if (t < 6) {
        const float h = STEP_F;
        float yt[10];
        #pragma unroll
        for (int n = 0; n < 10; ++n) yt[n] = ysv[t * 10 + n] + (float)n * h;
        float r[8];
        const float k6h2 = 6.0f / (h * h);
        #pragma unroll
        for (int i = 0; i < 8; ++i) r[i] = k6h2 * (yt[i] - 2.0f * yt[i+1] + yt[i+2]);
        float cp[8], dp[8];
        cp[0] = 0.25f; dp[0] = r[0] * 0.25f;
        #pragma unroll
        for (int i = 1; i < 8; ++i) {
            float m = 4.0f - cp[i-1];
            cp[i] = 1.0f / m;
            dp[i] = (r[i] - dp[i-1]) / m;
        }
        float M[10];
        M[0] = 0.0f; M[9] = 0.0f; M[8] = dp[7];
        #pragma unroll
        for (int i = 6; i >= 0; --i) M[i+1] = dp[i] - cp[i] * M[i+2];
        float* cg = coef + ((size_t)b * 6 + t) * 36;
        #pragma unroll
        for (int i = 0; i < 9; ++i) {
            float ca = (M[i+1] - M[i]) / (6.0f * h);
            float cb = M[i] * 0.5f;
            float cc = (yt[i+1] - yt[i]) / h - (M[i+1] + 2.0f * M[i]) * (h / 6.0f);
            float cd = yt[i];
            cfl[t*36 + i]      = ca;  cg[i]      = ca;
            cfl[t*36 + 9 + i]  = cb;  cg[9 + i]  = cb;
            cfl[t*36 + 18 + i] = cc;  cg[18 + i] = cc;
            cfl[t*36 + 27 + i] = cd;  cg[27 + i] = cd;
        }
    }
    __syncthreads();
    for (int i = t; i < 1530; i += 256) {
        int v = i % 255, ec = i / 255;
        float val = (float)v * (1.0f / 255.0f);
        int vi = (int)floorf(val / STEP_F);
        vi = vi < 0 ? 0 : (vi > 8 ? 8 : vi);
        float vf = val - (float)vi * STEP_F;
        const float* c = cfl + ec * 36;
        int e = ec / 3, ch = ec % 3;
        spl[(((size_t)e * 64 + b) * 3 + ch) * 255 + v] =
            ((c[vi]*vf + c[9+vi])*vf + c[18+vi])*vf + c[27+vi];
    }
}

// ---------------- apply spline: ds_bpermute coefficient gather ----------------
__global__ __launch_bounds__(256) void apply2_k(const float* __restrict__ batch,
                                                const float* __restrict__ coef,
                                                float* __restrict__ out)
{
    int bc = blockIdx.y;
    int b = bc / 3, ch = bc % 3;
    int lane = threadIdx.x & 63;
    int j = lane < 9 ? lane : 8;
    const float* c0p = coef + ((size_t)(b * 6 + 0 + ch)) * 36;
    const float* c1p = coef + ((size_t)(b * 6 + 3 + ch)) * 36;
    float A0 = c0p[j], B0 = c0p[9 + j], C0 = c0p[18 + j], D0 = c0p[27 + j];
    float A1 = c1p[j], B1 = c1p[9 + j], C1 = c1p[18 + j], D1 = c1p[27 + j];

    const int P = 65536;
    size_t base = ((size_t)b * 3 + ch) * P;
    int p0 = (blockIdx.x * blockDim.x + threadIdx.x) * 4;

    float4 xv = *(const float4*)(batch + base + p0);
    float xs[4] = {xv.x, xv.y, xv.z, xv.w};
    float r0[4], r1[4];
    #pragma unroll
    for (int k = 0; k < 4; ++k) {
        float x = xs[k];
        int xi = (int)floorf(x / STEP_F);
        xi = xi < 0 ? 0 : (xi > 8 ? 8 : xi);
        float xf = x - (float)xi * STEP_F;
        int bidx = xi << 2;
        float ga0 = __int_as_float(__builtin_amdgcn_ds_bpermute(bidx, __float_as_int(A0)));
        float gb0 = __int_as_float(__builtin_amdgcn_ds_bpermute(bidx, __float_as_int(B0)));
        float gc0 = __int_as_float(__builtin_amdgcn_ds_bpermute(bidx, __float_as_int(C0)));
        float gd0 = __int_as_float(__builtin_amdgcn_ds_bpermute(bidx, __float_as_int(D0)));
        float ga1 = __int_as_float(__builtin_amdgcn_ds_bpermute(bidx, __float_as_int(A1)));
        float gb1 = __int_as_float(__builtin_amdgcn_ds_bpermute(bidx, __float_as_int(B1)));
        float gc1 = __int_as_float(__builtin_amdgcn_ds_bpermute(bidx, __float_as_int(C1)));
        float gd1 = __int_as_float(__builtin_amdgcn_ds_bpermute(bidx, __float_as_int(D1)));
        r0[k] = fmaf(fmaf(fmaf(ga0, xf, gb0), xf, gc0), xf, gd0);
        r1[k] = fmaf(fmaf(fmaf(ga1, xf, gb1), xf, gc1), xf, gd1);
    }
    float4 o0 = {r0[0], r0[1], r0[2], r0[3]};
    float4 o1 = {r1[0], r1[1], r1[2], r1[3]};
    size_t off0 = (((size_t)0 * 64 + b) * 3 + ch) * P + p0;
    size_t off1 = (((size_t)1 * 64 + b) * 3 + ch) * P + p0;
    *(float4*)(out + off0) = o0;
    *(float4*)(out + off1) = o1;
}

extern "C" void kernel_launch(void* const* d_in, const int* in_sizes, int n_in,
                              void* d_out, int out_size, void* d_ws, size_t ws_size,
                              hipStream_t stream) {
    const float* batch = (const float*)d_in[0];
    const float* w1 = (const float*)d_in[1];  const float* b1 = (const float*)d_in[2];
    const float* w2 = (const float*)d_in[3];  const float* b2 = (const float*)d_in[4];
    const float* w3 = (const float*)d_in[5];  const float* b3 = (const float*)d_in[6];
    const float* w4 = (const float*)d_in[7];  const float* b4 = (const float*)d_in[8];
    const float* w5 = (const float*)d_in[9];  const float* b5 = (const float*)d_in[10];
    const float* bn2g = (const float*)d_in[11]; const float* bn2b = (const float*)d_in[12];
    const float* bn2m = (const float*)d_in[13]; const float* bn2v = (const float*)d_in[14];
    const float* bn3g = (const float*)d_in[15]; const float* bn3b = (const float*)d_in[16];
    const float* bn3m = (const float*)d_in[17]; const float* bn3v = (const float*)d_in[18];
    const float* bn4g = (const float*)d_in[19]; const float* bn4b = (const float*)d_in[20];
    const float* bn4m = (const float*)d_in[21]; const float* bn4v = (const float*)d_in[22];
    const float* bn5g = (const float*)d_in[23]; const float* bn5b = (const float*)d_in[24];
    const float* bn5m = (const float*)d_in[25]; const float* bn5v = (const float*)d_in[26];
    const float* l1w = (const float*)d_in[27]; const float* l1b = (const float*)d_in[28];
    const float* l2w = (const float*)d_in[29]; const float* l2b = (const float*)d_in[30];

    float* outp = (float*)d_out;
    float* y1 = outp;                 // 64*8*127*128  = 8,323,072
    float* y2 = y1 + 8323072;         // 64*16*63*64   = 4,128,768
    float* y3 = y2 + 4128768;         // 64*32*31*32   = 2,031,616
    float* y4 = y3 + 2031616;         // 64*64*15*16   =   983,040
    // end = 15,466,496 < 25,165,824 -> safe; fully overwritten by apply2.

    float* coef  = (float*)d_ws;      // 13,824 floats
    float* featw = coef + 13824;      // 8,192 floats
    float* spl   = outp + 25165824;

    const int TPB = 256;
    conv1_k<<<1016, TPB, 0, stream>>>(batch, w1, b1, y1);
    conv2_k<<<dim3(16, 64), TPB, 0, stream>>>(y1, w2, b2, bn2g, bn2b, bn2m, bn2v, y2);
    conv3_k<<<dim3(16, 64), TPB, 0, stream>>>(y2, w3, b3, bn3g, bn3b, bn3m, bn3v, y3);
    conv4_k<<<dim3(16, 64), TPB, 0, stream>>>(y3, w4, b4, bn4g, bn4b, bn4m, bn4v, y4);
    conv5w_k<<<dim3(16, 64), TPB, 0, stream>>>(y4, w5, b5, bn5g, bn5b, bn5m, bn5v, featw);
    tail_k<<<64, TPB, 0, stream>>>(featw, l1w, l1b, l2w, l2b, coef, spl);
    {
        dim3 grid(64, 192);
        apply2_k<<<grid, TPB, 0, stream>>>(batch, coef, outp);
    }
}

// Round 14
// 130.229 us; speedup vs baseline: 5.9894x; 1.0259x over previous
//
#include <hip/hip_runtime.h>
#include <hip/hip_bf16.h>

#define STEP_F (1.0f/9.0f)

typedef float f4 __attribute__((ext_vector_type(4)));

// ---------------- conv1: 3->8, 256x256 -> 127x127 (stored 127x128), stride 2, relu ----
__global__ __launch_bounds__(256) void conv1_k(const float* __restrict__ x,
                                               const float* __restrict__ w,
                                               const float* __restrict__ bias,
                                               float* __restrict__ y)
{
    int idx = blockIdx.x * 256 + threadIdx.x;
    int owg = idx & 31;
    int t1  = idx >> 5;
    int oh  = t1 % 127;
    int b   = t1 / 127;
    int iw0 = owg * 8;
    int ih0 = oh * 2;
    const float* xb = x + (size_t)b * 3 * 65536;

    float acc[8][4];
    #pragma unroll
    for (int c = 0; c < 8; ++c)
        #pragma unroll
        for (int t = 0; t < 4; ++t) acc[c][t] = 0.0f;

    #pragma unroll
    for (int ci = 0; ci < 3; ++ci) {
        float r[3][10];
        #pragma unroll
        for (int kh = 0; kh < 3; ++kh) {
            const float* row = xb + ci * 65536 + (ih0 + kh) * 256;
            #pragma unroll
            for (int t = 0; t < 5; ++t) {
                int c = iw0 + 2 * t; if (c > 254) c = 254;
                float2 v = *(const float2*)(row + c);
                r[kh][2*t] = v.x; r[kh][2*t+1] = v.y;
            }
        }
        #pragma unroll
        for (int co = 0; co < 8; ++co) {
            float wr[9];
            #pragma unroll
            for (int k = 0; k < 9; ++k) wr[k] = w[(co * 3 + ci) * 9 + k];
            #pragma unroll
            for (int t = 0; t < 4; ++t) {
                float a = acc[co][t];
                #pragma unroll
                for (int kh = 0; kh < 3; ++kh)
                    a = fmaf(r[kh][2*t+0], wr[kh*3+0],
                        fmaf(r[kh][2*t+1], wr[kh*3+1],
                        fmaf(r[kh][2*t+2], wr[kh*3+2], a)));
                acc[co][t] = a;
            }
        }
    }
    int ow0 = owg * 4;
    #pragma unroll
    for (int co = 0; co < 8; ++co) {
        float bs = bias[co];
        float4 o;
        o.x = fmaxf(acc[co][0] + bs, 0.0f);
        o.y = fmaxf(acc[co][1] + bs, 0.0f);
        o.z = fmaxf(acc[co][2] + bs, 0.0f);
        o.w = fmaxf(acc[co][3] + bs, 0.0f);
        *(float4*)(y + (((size_t)b * 8 + co) * 127 + oh) * 128 + ow0) = o;
    }
}

// ---------------- conv2: 8->16, LDS tile, full-width lanes (R6-proven) ----------
__global__ __launch_bounds__(256) void conv2_k(
    const float* __restrict__ x,      // y1 [64][8][127][128]
    const float* __restrict__ w, const float* __restrict__ bias,
    const float* __restrict__ g, const float* __restrict__ be,
    const float* __restrict__ mn, const float* __restrict__ vr,
    float* __restrict__ y)            // y2 [64][16][63][64]
{
    __shared__ float lds[8 * 9 * 128 + 192];
    const int ohg = blockIdx.x;       // 0..15
    const int b   = blockIdx.y;
    const int oh0 = ohg * 4;
    const int ih0 = oh0 * 2;
    const int tid = threadIdx.x;

    {
        const int col = tid & 127;
        const int rp  = tid >> 7;
        const int rows = (127 - ih0) < 9 ? (127 - ih0) : 9;
        #pragma unroll
        for (int ci = 0; ci < 8; ++ci) {
            const float* gp = x + (((size_t)b * 8 + ci) * 127 + ih0) * 128 + col;
            float* lp = lds + ci * 1152 + col;
            for (int rr = rp; rr < rows; rr += 2)
                lp[rr * 128] = gp[rr * 128];
        }
    }
    __syncthreads();

    const int lane = tid & 63;
    const int wv   = __builtin_amdgcn_readfirstlane(tid >> 6);
    const int ow   = lane;
    const int co0  = wv * 4;

    float acc[4][4];
    #pragma unroll
    for (int c = 0; c < 4; ++c)
        #pragma unroll
        for (int j = 0; j < 4; ++j) acc[c][j] = 0.0f;

    #pragma unroll 2
    for (int ci = 0; ci < 8; ++ci) {
        float wr[4][9];
        #pragma unroll
        for (int c = 0; c < 4; ++c) {
            const int wb = __builtin_amdgcn_readfirstlane(((co0 + c) * 8 + ci) * 9);
            #pragma unroll
            for (int k = 0; k < 9; ++k) wr[c][k] = w[wb + k];
        }
        const float* lci = lds + ci * 1152;
        #pragma unroll
        for (int r = 0; r < 9; ++r) {
            float2 x01 = *(const float2*)&lci[r * 128 + 2 * ow];
            float  x2  = lci[r * 128 + 2 * ow + 2];
            #pragma unroll
            for (int kh = 0; kh < 3; ++kh) {
                const int jj = r - kh;
                if (jj >= 0 && (jj & 1) == 0 && (jj >> 1) < 4) {
                    const int j = jj >> 1;
                    #pragma unroll
                    for (int c = 0; c < 4; ++c)
                        acc[c][j] = fmaf(x01.x, wr[c][kh*3+0],
                                    fmaf(x01.y, wr[c][kh*3+1],
                                    fmaf(x2,    wr[c][kh*3+2], acc[c][j])));
                }
            }
        }
    }

    if (ow < 63) {
        #pragma unroll
        for (int c = 0; c < 4; ++c) {
            const int co = co0 + c;
            const float bs = bias[co];
            const float s  = g[co] / sqrtf(vr[co] + 1e-5f);
            const float sh = be[co] - mn[co] * s;
            #pragma unroll
            for (int j = 0; j < 4; ++j) {
                int oh = oh0 + j;
                if (oh < 63)
                    y[(((size_t)b * 16 + co) * 63 + oh) * 64 + ow] =
                        fmaxf(acc[c][j] + bs, 0.0f) * s + sh;
            }
        }
    }
}

// ---------------- conv3: 16->32, direct-from-L2 (R6-proven, b-major locality) -------
__global__ __launch_bounds__(256) void conv3_k(
    const float* __restrict__ x,      // y2 [64][16][63][64]
    const float* __restrict__ w, const float* __restrict__ bias,
    const float* __restrict__ g, const float* __restrict__ be,
    const float* __restrict__ mn, const float* __restrict__ vr,
    float* __restrict__ y)            // y3 [64][32][31][32]
{
    const int ohg = blockIdx.x & 7;
    const int coh = blockIdx.x >> 3;
    const int b   = blockIdx.y;
    const int lane = threadIdx.x & 63;
    const int wv   = __builtin_amdgcn_readfirstlane(threadIdx.x >> 6);
    const int ow   = lane & 31;
    const int ohl  = lane >> 5;
    const int co0  = coh * 16 + wv * 4;
    const int ihb  = ohg * 8 + ohl * 4;

    float acc[4][2];
    #pragma unroll
    for (int c = 0; c < 4; ++c) { acc[c][0] = 0.0f; acc[c][1] = 0.0f; }

    #pragma unroll 4
    for (int ci = 0; ci < 16; ++ci) {
        const float* gp = x + (((size_t)b * 16 + ci) * 63) * 64 + 2 * ow;
        f4 rv[5];
        #pragma unroll
        for (int r = 0; r < 5; ++r) {
            int ih = ihb + r; ih = ih > 62 ? 62 : ih;
            rv[r] = *(const f4*)(gp + ih * 64);
        }
        float wr[4][9];
        #pragma unroll
        for (int c = 0; c < 4; ++c) {
            const int wb = __builtin_amdgcn_readfirstlane(((co0 + c) * 16 + ci) * 9);
            #pragma unroll
            for (int k = 0; k < 9; ++k) wr[c][k] = w[wb + k];
        }
        #pragma unroll
        for (int j = 0; j < 2; ++j)
            #pragma unroll
            for (int kh = 0; kh < 3; ++kh) {
                const f4 v = rv[2*j + kh];
                #pragma unroll
                for (int c = 0; c < 4; ++c)
                    acc[c][j] = fmaf(v[0], wr[c][kh*3+0],
                                fmaf(v[1], wr[c][kh*3+1],
                                fmaf(v[2], wr[c][kh*3+2], acc[c][j])));
            }
    }

    if (ow < 31) {
        #pragma unroll
        for (int c = 0; c < 4; ++c) {
            const int co = co0 + c;
            const float bs = bias[co];
            const float s  = g[co] / sqrtf(vr[co] + 1e-5f);
            const float sh = be[co] - mn[co] * s;
            #pragma unroll
            for (int j = 0; j < 2; ++j) {
                int oh = ohg * 4 + ohl * 2 + j;
                if (oh < 31)
                    y[(((size_t)b * 32 + co) * 31 + oh) * 32 + ow] =
                        fmaxf(acc[c][j] + bs, 0.0f) * s + sh;
            }
        }
    }
}

// ---------------- conv4: 32->64, direct-from-L2 (R6-proven, b-major locality) -------
__global__ __launch_bounds__(256) void conv4_k(
    const float* __restrict__ x,      // y3 [64][32][31][32]
    const float* __restrict__ w, const float* __restrict__ bias,
    const float* __restrict__ g, const float* __restrict__ be,
    const float* __restrict__ mn, const float* __restrict__ vr,
    float* __restrict__ y)            // y4 [64][64][15][16]
{
    const int ohg = blockIdx.x & 3;
    const int cog = blockIdx.x >> 2;
    const int b   = blockIdx.y;
    const int lane = threadIdx.x & 63;
    const int wv   = __builtin_amdgcn_readfirstlane(threadIdx.x >> 6);
    const int ow   = lane & 15;
    const int ohl  = lane >> 4;
    const int oh   = ohg * 4 + ohl;
    const int co0  = cog * 16 + wv * 4;
    const int ihb  = 2 * oh;

    float acc[4];
    #pragma unroll
    for (int c = 0; c < 4; ++c) acc[c] = 0.0f;

    #pragma unroll 4
    for (int ci = 0; ci < 32; ++ci) {
        const float* gp = x + (((size_t)b * 32 + ci) * 31) * 32 + 2 * ow;
        f4 rv[3];
        #pragma unroll
        for (int r = 0; r < 3; ++r) {
            int ih = ihb + r; ih = ih > 30 ? 30 : ih;
            rv[r] = *(const f4*)(gp + ih * 32);
        }
        float wr[4][9];
        #pragma unroll
        for (int c = 0; c < 4; ++c) {
            const int wb = __builtin_amdgcn_readfirstlane(((co0 + c) * 32 + ci) * 9);
            #pragma unroll
            for (int k = 0; k < 9; ++k) wr[c][k] = w[wb + k];
        }
        #pragma unroll
        for (int kh = 0; kh < 3; ++kh) {
            const f4 v = rv[kh];
            #pragma unroll
            for (int c = 0; c < 4; ++c)
                acc[c] = fmaf(v[0], wr[c][kh*3+0],
                         fmaf(v[1], wr[c][kh*3+1],
                         fmaf(v[2], wr[c][kh*3+2], acc[c])));
        }
    }

    if (ow < 15 && oh < 15) {
        #pragma unroll
        for (int c = 0; c < 4; ++c) {
            const int co = co0 + c;
            const float bs = bias[co];
            const float s  = g[co] / sqrtf(vr[co] + 1e-5f);
            const float sh = be[co] - mn[co] * s;
            y[(((size_t)b * 64 + co) * 15 + oh) * 16 + ow] =
                fmaxf(acc[c] + bs, 0.0f) * s + sh;
        }
    }
}

// ---------------- conv5 + BN + relu + mean: f4-padded LDS weights ----------------
// Grid (16 cog, 64 b). Weights padded 9->12 floats per (co,ci): 3x ds_read_b128
// per co (24 DS issues/ci, under the 144cy FMA floor). Zero s_loads in loop.
__global__ __launch_bounds__(256) void conv5v3_k(
    const float* __restrict__ x,      // y4 [64][64][15][16]
    const float* __restrict__ w, const float* __restrict__ bias,
    const float* __restrict__ g, const float* __restrict__ be,
    const float* __restrict__ mn, const float* __restrict__ vr,
    float* __restrict__ feat)         // [64][128]
{
    __shared__ float lw[8 * 64 * 12];      // 6144 floats, padded
    __shared__ float red[4 * 580 + 16];
    const int co0  = blockIdx.x * 8;
    const int b    = blockIdx.y;
    const int tid  = threadIdx.x;

    {   // stage weights with 9->12 padding (pad slots unread garbage-safe)
        const float* wp = w + (size_t)co0 * 576;
        for (int i = tid; i < 4608; i += 256)
            lw[(i / 9) * 12 + (i % 9)] = wp[i];
    }
    __syncthreads();

    const int wv   = __builtin_amdgcn_readfirstlane(tid >> 6);
    const int lane = tid & 63;
    const int pr = lane >> 3, pc = lane & 7;

    float acc[8];
    #pragma unroll
    for (int c = 0; c < 8; ++c) acc[c] = 0.0f;

    #pragma unroll 2
    for (int i = 0; i < 16; ++i) {
        const int ci = wv * 16 + i;
        const float* gp = x + (((size_t)b * 64 + ci) * 15) * 16 + 2 * pc;
        f4 rv[3];
        #pragma unroll
        for (int r = 0; r < 3; ++r) {
            int ih = 2 * pr + r; ih = ih > 14 ? 14 : ih;
            rv[r] = *(const f4*)(gp + ih * 16);
        }
        float wr[8][9];
        #pragma unroll
        for (int c = 0; c < 8; ++c) {
            const f4* wl = (const f4*)(lw + (c * 64 + ci) * 12);  // uniform -> b128 broadcast
            f4 a0 = wl[0], a1 = wl[1], a2 = wl[2];
            wr[c][0]=a0[0]; wr[c][1]=a0[1]; wr[c][2]=a0[2]; wr[c][3]=a0[3];
            wr[c][4]=a1[0]; wr[c][5]=a1[1]; wr[c][6]=a1[2]; wr[c][7]=a1[3];
            wr[c][8]=a2[0];
        }
        #pragma unroll
        for (int kh = 0; kh < 3; ++kh) {
            const f4 v = rv[kh];
            #pragma unroll
            for (int c = 0; c < 8; ++c)
                acc[c] = fmaf(v[0], wr[c][kh*3+0],
                         fmaf(v[1], wr[c][kh*3+1],
                         fmaf(v[2], wr[c][kh*3+2], acc[c])));
        }
    }

    #pragma unroll
    for (int c = 0; c < 8; ++c) red[wv * 580 + lane * 9 + c] = acc[c];
    __syncthreads();
    if (wv == 0) {
        const bool act = (pr < 7) && (pc < 7);
        #pragma unroll
        for (int c = 0; c < 8; ++c) {
            float v = red[lane*9+c] + red[580+lane*9+c]
                    + red[1160+lane*9+c] + red[1740+lane*9+c];
            const int co = co0 + c;
            const float s = g[co] / sqrtf(vr[co] + 1e-5f);
            v = fmaxf(v + bias[co], 0.0f) * s + (be[co] - mn[co] * s);
            v = act ? v : 0.0f;
            #pragma unroll
            for (int off = 32; off; off >>= 1) v += __shfl_xor(v, off, 64);
            if (lane == 0) feat[(size_t)b * 128 + co] = v * (1.0f / 49.0f);
        }
    }
}

// ---------------- fused tail: fc1 + fc2 + Thomas + splines LUT ----------------
__global__ __launch_bounds__(256) void tail_k(
    const float* __restrict__ featg, const float* __restrict__ l1w,
    const float* __restrict__ l1b, const float* __restrict__ l2w,
    const float* __restrict__ l2b, float* __restrict__ coef,
    float* __restrict__ spl)
{
    __shared__ float feat[128];
    __shared__ float hh[128];
    __shared__ float ysv[64];
    __shared__ float cfl[216];
    const int b = blockIdx.x, t = threadIdx.x;

    if (t < 128) feat[t] = featg[(size_t)b * 128 + t];
    __syncthreads();
    if (t < 128) {
        const float4* wp = (const float4*)(l1w + (size_t)t * 128);
        float s = l1b[t];
        #pragma unroll 8
        for (int k = 0; k < 32; ++k) {
            float4 v = wp[k];
            s += v.x*feat[4*k] + v.y*feat[4*k+1] + v.z*feat[4*k+2] + v.w*feat[4*k+3];
        }
        hh[t] = fmaxf(s, 0.0f);
    }
    __syncthreads();
    if (t < 60) {
        const float4* wp = (const float4*)(l2w + (size_t)t * 128);
        float s = l2b[t];
        #pragma unroll 8
        for (int k = 0; k < 32; ++k) {
            float4 v = wp[k];
            s += v.x*hh[4*k] + v.y*hh[4*k+1] + v.z*hh[4*k+2] + v.w*hh[4*k+3];
        }
        ysv[t] = s;
    }
    __syncthreads();
    if (t < 6) {
        const float h = STEP_F;
        float yt[10];
        #pragma unroll
        for (int n = 0; n < 10; ++n) yt[n] = ysv[t * 10 + n] + (float)n * h;
        float r[8];
        const float k6h2 = 6.0f / (h * h);
        #pragma unroll
        for (int i = 0; i < 8; ++i) r[i] = k6h2 * (yt[i] - 2.0f * yt[i+1] + yt[i+2]);
        float cp[8], dp[8];
        cp[0] = 0.25f; dp[0] = r[0] * 0.25f;
        #pragma unroll
        for (int i = 1; i < 8; ++i) {
            float m = 4.0f - cp[i-1];
            cp[i] = 1.0f / m;
            dp[i] = (r[i] - dp[i-1]) / m;
        }
        float M[10];
        M[0] = 0.0f; M[9] = 0.0f; M[8] = dp[7];
        #pragma unroll
        for (int i = 6; i >= 0; --i) M[i+1] = dp[i] - cp[i] * M[i+2];
        float* cg = coef + ((size_t)b * 6 + t) * 36;
        #pragma unroll
        for (int i = 0; i < 9; ++i) {
            float ca = (M[i+1] - M[i]) / (6.0f * h);
            float cb = M[i] * 0.5f;
            float cc = (yt[i+1] - yt[i]) / h - (M[i+1] + 2.0f * M[i]) * (h / 6.0f);
            float cd = yt[i];
            cfl[t*36 + i]      = ca;  cg[i]      = ca;
            cfl[t*36 + 9 + i]  = cb;  cg[9 + i]  = cb;
            cfl[t*36 + 18 + i] = cc;  cg[18 + i] = cc;
            cfl[t*36 + 27 + i] = cd;  cg[27 + i] = cd;
        }
    }
    __syncthreads();
    for (int i = t; i < 1530; i += 256) {
        int v = i % 255, ec = i / 255;
        float val = (float)v * (1.0f / 255.0f);
        int vi = (int)floorf(val / STEP_F);
        vi = vi < 0 ? 0 : (vi > 8 ? 8 : vi);
        float vf = val - (float)vi * STEP_F;
        const float* c = cfl + ec * 36;
        int e = ec / 3, ch = ec % 3;
        spl[(((size_t)e * 64 + b) * 3 + ch) * 255 + v] =
            ((c[vi]*vf + c[9+vi])*vf + c[18+vi])*vf + c[27+vi];
    }
}

// ---------------- apply spline: ds_bpermute coefficient gather ----------------
__global__ __launch_bounds__(256) void apply2_k(const float* __restrict__ batch,
                                                const float* __restrict__ coef,
                                                float* __restrict__ out)
{
    int bc = blockIdx.y;
    int b = bc / 3, ch = bc % 3;
    int lane = threadIdx.x & 63;
    int j = lane < 9 ? lane : 8;
    const float* c0p = coef + ((size_t)(b * 6 + 0 + ch)) * 36;
    const float* c1p = coef + ((size_t)(b * 6 + 3 + ch)) * 36;
    float A0 = c0p[j], B0 = c0p[9 + j], C0 = c0p[18 + j], D0 = c0p[27 + j];
    float A1 = c1p[j], B1 = c1p[9 + j], C1 = c1p[18 + j], D1 = c1p[27 + j];

    const int P = 65536;
    size_t base = ((size_t)b * 3 + ch) * P;
    int p0 = (blockIdx.x * blockDim.x + threadIdx.x) * 4;

    float4 xv = *(const float4*)(batch + base + p0);
    float xs[4] = {xv.x, xv.y, xv.z, xv.w};
    float r0[4], r1[4];
    #pragma unroll
    for (int k = 0; k < 4; ++k) {
        float x = xs[k];
        int xi = (int)floorf(x / STEP_F);
        xi = xi < 0 ? 0 : (xi > 8 ? 8 : xi);
        float xf = x - (float)xi * STEP_F;
        int bidx = xi << 2;
        float ga0 = __int_as_float(__builtin_amdgcn_ds_bpermute(bidx, __float_as_int(A0)));
        float gb0 = __int_as_float(__builtin_amdgcn_ds_bpermute(bidx, __float_as_int(B0)));
        float gc0 = __int_as_float(__builtin_amdgcn_ds_bpermute(bidx, __float_as_int(C0)));
        float gd0 = __int_as_float(__builtin_amdgcn_ds_bpermute(bidx, __float_as_int(D0)));
        float ga1 = __int_as_float(__builtin_amdgcn_ds_bpermute(bidx, __float_as_int(A1)));
        float gb1 = __int_as_float(__builtin_amdgcn_ds_bpermute(bidx, __float_as_int(B1)));
        float gc1 = __int_as_float(__builtin_amdgcn_ds_bpermute(bidx, __float_as_int(C1)));
        float gd1 = __int_as_float(__builtin_amdgcn_ds_bpermute(bidx, __float_as_int(D1)));
        r0[k] = fmaf(fmaf(fmaf(ga0, xf, gb0), xf, gc0), xf, gd0);
        r1[k] = fmaf(fmaf(fmaf(ga1, xf, gb1), xf, gc1), xf, gd1);
    }
    float4 o0 = {r0[0], r0[1], r0[2], r0[3]};
    float4 o1 = {r1[0], r1[1], r1[2], r1[3]};
    size_t off0 = (((size_t)0 * 64 + b) * 3 + ch) * P + p0;
    size_t off1 = (((size_t)1 * 64 + b) * 3 + ch) * P + p0;
    *(float4*)(out + off0) = o0;
    *(float4*)(out + off1) = o1;
}

extern "C" void kernel_launch(void* const* d_in, const int* in_sizes, int n_in,
                              void* d_out, int out_size, void* d_ws, size_t ws_size,
                              hipStream_t stream) {
    const float* batch = (const float*)d_in[0];
    const float* w1 = (const float*)d_in[1];  const float* b1 = (const float*)d_in[2];
    const float* w2 = (const float*)d_in[3];  const float* b2 = (const float*)d_in[4];
    const float* w3 = (const float*)d_in[5];  const float* b3 = (const float*)d_in[6];
    const float* w4 = (const float*)d_in[7];  const float* b4 = (const float*)d_in[8];
    const float* w5 = (const float*)d_in[9];  const float* b5 = (const float*)d_in[10];
    const float* bn2g = (const float*)d_in[11]; const float* bn2b = (const float*)d_in[12];
    const float* bn2m = (const float*)d_in[13]; const float* bn2v = (const float*)d_in[14];
    const float* bn3g = (const float*)d_in[15]; const float* bn3b = (const float*)d_in[16];
    const float* bn3m = (const float*)d_in[17]; const float* bn3v = (const float*)d_in[18];
    const float* bn4g = (const float*)d_in[19]; const float* bn4b = (const float*)d_in[20];
    const float* bn4m = (const float*)d_in[21]; const float* bn4v = (const float*)d_in[22];
    const float* bn5g = (const float*)d_in[23]; const float* bn5b = (const float*)d_in[24];
    const float* bn5m = (const float*)d_in[25]; const float* bn5v = (const float*)d_in[26];
    const float* l1w = (const float*)d_in[27]; const float* l1b = (const float*)d_in[28];
    const float* l2w = (const float*)d_in[29]; const float* l2b = (const float*)d_in[30];

    float* outp = (float*)d_out;
    float* y1 = outp;                 // 64*8*127*128  = 8,323,072
    float* y2 = y1 + 8323072;         // 64*16*63*64   = 4,128,768
    float* y3 = y2 + 4128768;         // 64*32*31*32   = 2,031,616
    float* y4 = y3 + 2031616;         // 64*64*15*16   =   983,040

    float* coef  = (float*)d_ws;      // 13,824 floats
    float* featw = coef + 13824;      // 8,192 floats
    float* spl   = outp + 25165824;

    const int TPB = 256;
    conv1_k<<<1016, TPB, 0, stream>>>(batch, w1, b1, y1);
    conv2_k<<<dim3(16, 64), TPB, 0, stream>>>(y1, w2, b2, bn2g, bn2b, bn2m, bn2v, y2);
    conv3_k<<<dim3(16, 64), TPB, 0, stream>>>(y2, w3, b3, bn3g, bn3b, bn3m, bn3v, y3);
    conv4_k<<<dim3(16, 64), TPB, 0, stream>>>(y3, w4, b4, bn4g, bn4b, bn4m, bn4v, y4);
    conv5v3_k<<<dim3(16, 64), TPB, 0, stream>>>(y4, w5, b5, bn5g, bn5b, bn5m, bn5v, featw);
    tail_k<<<64, TPB, 0, stream>>>(featw, l1w, l1b, l2w, l2b, coef, spl);
    {
        dim3 grid(64, 192);
        apply2_k<<<grid, TPB, 0, stream>>>(batch, coef, outp);
    }
}